// Round 1
// baseline (78.063 us; speedup 1.0000x reference)
//
#include <hip/hip_runtime.h>
#include <math.h>

#define D      2048
#define KSEL   256
#define NT     256          // threads per block
#define VPT    8            // values per thread (NT*VPT == D)
#define NBINS  256
#define CAND_CAP 512
#define HIST_SCALE 32.0f    // bins cover |z| in [0, 8); clamp above

__device__ __forceinline__ float gelu_exact(float x) {
    return 0.5f * x * (1.0f + erff(x * 0.70710678118654752f));
}

__device__ __forceinline__ int binof(float a) {
    int b = (int)(a * HIST_SCALE);
    return b > (NBINS - 1) ? (NBINS - 1) : b;
}

// Block-wide sum of two floats across 256 threads (4 waves). Broadcasts result.
__device__ __forceinline__ void breduce2(float& a, float& b) {
    __shared__ float buf[8];
    for (int o = 32; o > 0; o >>= 1) {
        a += __shfl_down(a, o, 64);
        b += __shfl_down(b, o, 64);
    }
    int wave = threadIdx.x >> 6;
    int lane = threadIdx.x & 63;
    __syncthreads();              // protect buf from any previous use
    if (lane == 0) { buf[wave * 2] = a; buf[wave * 2 + 1] = b; }
    __syncthreads();
    a = buf[0] + buf[2] + buf[4] + buf[6];
    b = buf[1] + buf[3] + buf[5] + buf[7];
}

// One block, 256 threads: precompute inv_std[D], ema_u[D], and scalars into ws.
__global__ __launch_bounds__(NT) void prep_kernel(
    const float* __restrict__ ema_mean,
    const float* __restrict__ ema_sq,
    const float* __restrict__ ema_out,
    const float* __restrict__ log_tau,
    const float* __restrict__ log_sigma_raw,
    const float* __restrict__ log_w_raw,
    float* __restrict__ ws)  // [0:D) inv_std, [D:2D) ema_u, [2D..2D+2] tau,sigma,w
{
    __shared__ float red[4];
    int tid = threadIdx.x;
    float ss = 0.f;
    for (int i = tid; i < D; i += NT) {
        float m = ema_mean[i];
        float v = ema_sq[i] - m * m;
        v = fmaxf(v, 1e-6f);
        ws[i] = 1.0f / sqrtf(v);
        float e = ema_out[i];
        ss += e * e;
    }
    for (int o = 32; o > 0; o >>= 1) ss += __shfl_down(ss, o, 64);
    if ((tid & 63) == 0) red[tid >> 6] = ss;
    __syncthreads();
    float tot = red[0] + red[1] + red[2] + red[3];
    float inv_nrm = 1.0f / (sqrtf(tot) + 1e-8f);
    for (int i = tid; i < D; i += NT) {
        ws[D + i] = ema_out[i] * inv_nrm;
    }
    if (tid == 0) {
        ws[2 * D + 0] = expf(log_tau[0]);                       // tau
        ws[2 * D + 1] = log1pf(expf(log_sigma_raw[0])) + 0.01f; // sigma
        ws[2 * D + 2] = log1pf(expf(log_w_raw[0]));             // w
    }
}

// One block per row.
__global__ __launch_bounds__(NT) void row_kernel(
    const float* __restrict__ x,
    const float* __restrict__ ema_mean,
    const float* __restrict__ ws,
    float* __restrict__ out)
{
    __shared__ int   hist[NBINS];
    __shared__ float cand[CAND_CAP];
    __shared__ int   wsum[4];
    __shared__ int   nc_sh;
    __shared__ int   bsel_sh;
    __shared__ int   krem_sh;
    __shared__ float thr_sh;

    const int row = blockIdx.x;
    const int tid = threadIdx.x;
    const float* __restrict__ xr = x + (size_t)row * D;
    float* __restrict__ outr = out + (size_t)row * D;
    const float* __restrict__ inv_std = ws;
    const float* __restrict__ ema_u   = ws + D;
    const float tau   = ws[2 * D + 0];
    const float sigma = ws[2 * D + 1];
    const float w     = ws[2 * D + 2];

    hist[tid] = 0;
    if (tid == 0) nc_sh = 0;

    // ---- load row slice: 8 contiguous floats per thread ----
    float4 xa = ((const float4*)xr)[tid * 2];
    float4 xb = ((const float4*)xr)[tid * 2 + 1];
    float4 ma = ((const float4*)ema_mean)[tid * 2];
    float4 mb = ((const float4*)ema_mean)[tid * 2 + 1];
    float4 sa = ((const float4*)inv_std)[tid * 2];
    float4 sb = ((const float4*)inv_std)[tid * 2 + 1];
    float4 ua = ((const float4*)ema_u)[tid * 2];
    float4 ub = ((const float4*)ema_u)[tid * 2 + 1];

    float xv[VPT] = {xa.x, xa.y, xa.z, xa.w, xb.x, xb.y, xb.z, xb.w};
    float mv[VPT] = {ma.x, ma.y, ma.z, ma.w, mb.x, mb.y, mb.z, mb.w};
    float sv[VPT] = {sa.x, sa.y, sa.z, sa.w, sb.x, sb.y, sb.z, sb.w};
    float uv[VPT] = {ua.x, ua.y, ua.z, ua.w, ub.x, ub.y, ub.z, ub.w};

    float g[VPT], av[VPT];
    float dot = 0.f, nrm = 0.f;
#pragma unroll
    for (int j = 0; j < VPT; ++j) {
        float gg = gelu_exact(xv[j]);
        g[j] = gg;
        float z = (xv[j] - mv[j]) * sv[j];
        av[j] = fabsf(z);
        dot += gg * uv[j];
        nrm += gg * gg;
    }

    __syncthreads();  // hist zero visible
#pragma unroll
    for (int j = 0; j < VPT; ++j) {
        atomicAdd(&hist[binof(av[j])], 1);
    }
    __syncthreads();

    // ---- parallel suffix scan from the top to find boundary bin ----
    {
        int bin = (NBINS - 1) - tid;       // reversed order: tid 0 -> bin 255
        int h = hist[bin];
        int p = h;
        for (int o = 1; o < 64; o <<= 1) {
            int t = __shfl_up(p, o, 64);
            if ((tid & 63) >= o) p += t;
        }
        if ((tid & 63) == 63) wsum[tid >> 6] = p;
        __syncthreads();
        int off = 0;
        for (int wv = 0; wv < (tid >> 6); ++wv) off += wsum[wv];
        int suf_incl = p + off;            // count of values in bins >= bin
        int suf_excl = suf_incl - h;       // count of values in bins >  bin
        if (suf_excl < KSEL && suf_incl >= KSEL) {
            bsel_sh = bin;
            krem_sh = KSEL - suf_excl;     // rank needed within boundary bin
        }
        __syncthreads();
    }

    const int bsel = bsel_sh;
    const int krem = krem_sh;

    // ---- gather boundary-bin candidates ----
#pragma unroll
    for (int j = 0; j < VPT; ++j) {
        if (binof(av[j]) == bsel) {
            int p = atomicAdd(&nc_sh, 1);
            if (p < CAND_CAP) cand[p] = av[j];
        }
    }
    __syncthreads();

    // ---- exact krem-th largest among candidates (lane-parallel rank) ----
    {
        int n = nc_sh < CAND_CAP ? nc_sh : CAND_CAP;
        for (int i = tid; i < n; i += NT) {
            float v = cand[i];
            int gi = 0, ei = 0;
            for (int j = 0; j < n; ++j) {
                float c = cand[j];
                gi += (c > v);
                ei += (c == v);
            }
            if (gi < krem && krem <= gi + ei) thr_sh = v;
        }
        __syncthreads();
    }
    const float thr = thr_sh;

    // ---- sum of strictly-greater values + tie completion ----
    float s = 0.f, c = 0.f;
#pragma unroll
    for (int j = 0; j < VPT; ++j) {
        if (av[j] > thr) { s += av[j]; c += 1.f; }
    }
    breduce2(dot, nrm);
    breduce2(s, c);

    const float topk_sum  = s + ((float)KSEL - c) * thr;
    const float topk_mean = topk_sum * (1.0f / (float)KSEL);
    const float cosv = dot / fmaxf(sqrtf(nrm), 1e-12f);
    const float gate = expf(-tau * cosv) * (1.0f + w * tanhf(sigma * topk_mean));

    float4 oa, ob;
    oa.x = g[0] * gate; oa.y = g[1] * gate; oa.z = g[2] * gate; oa.w = g[3] * gate;
    ob.x = g[4] * gate; ob.y = g[5] * gate; ob.z = g[6] * gate; ob.w = g[7] * gate;
    ((float4*)outr)[tid * 2]     = oa;
    ((float4*)outr)[tid * 2 + 1] = ob;
}

extern "C" void kernel_launch(void* const* d_in, const int* in_sizes, int n_in,
                              void* d_out, int out_size, void* d_ws, size_t ws_size,
                              hipStream_t stream) {
    (void)in_sizes; (void)n_in; (void)out_size; (void)ws_size;
    const float* x         = (const float*)d_in[0];
    const float* ema_mean  = (const float*)d_in[1];
    const float* ema_sq    = (const float*)d_in[2];
    const float* ema_out   = (const float*)d_in[3];
    const float* log_tau   = (const float*)d_in[4];
    const float* log_sigma = (const float*)d_in[5];
    const float* log_w     = (const float*)d_in[6];
    float* out = (float*)d_out;
    float* ws  = (float*)d_ws;

    prep_kernel<<<1, NT, 0, stream>>>(ema_mean, ema_sq, ema_out,
                                      log_tau, log_sigma, log_w, ws);

    const int rows = 4 * 4096;  // B*T
    row_kernel<<<rows, NT, 0, stream>>>(x, ema_mean, ws, out);
}

// Round 2
// 55.703 us; speedup vs baseline: 1.4014x; 1.4014x over previous
//
#include <hip/hip_runtime.h>
#include <math.h>

#define D      2048
#define KSEL   256
#define NT     256          // threads per block; NT*8 == D
#define NBINS  256
#define INV_BIN 0.03125f    // bins of width 1/32 over |z| in [0,8)

// tanh-form GELU: x * sigmoid(1.5957691*x + 0.0713548*x^3)
// branchless; hardware v_exp + v_rcp. |err| vs exact erf-GELU < ~1e-3.
__device__ __forceinline__ float fast_gelu(float x) {
    float x2 = x * x;
    float t  = fmaf(x2, -0.0713548162f, -1.5957691216f);
    float e  = __expf(x * t);                       // e^{-(1.5958x+0.07135x^3)}
    return x * __builtin_amdgcn_rcpf(1.0f + e);     // x * sigmoid(...)
}

__global__ __launch_bounds__(NT) void fused_kernel(
    const float* __restrict__ x,
    const float* __restrict__ ema_mean,
    const float* __restrict__ ema_sq,
    const float* __restrict__ ema_out,
    const float* __restrict__ p_log_tau,
    const float* __restrict__ p_log_sigma,
    const float* __restrict__ p_log_w,
    float* __restrict__ out)
{
    __shared__ int   hist[NBINS];
    __shared__ int   wsum[4];
    __shared__ float red[4][4];
    __shared__ int   bsel_sh, krem_sh;
    __shared__ float sc_sh[3];

    const int tid = threadIdx.x;
    const size_t rowoff = (size_t)blockIdx.x * D;
    const float* __restrict__ xr = x + rowoff;

    hist[tid] = 0;
    if (tid == 0) {
        float lt = p_log_tau[0], ls = p_log_sigma[0], lw = p_log_w[0];
        sc_sh[0] = __expf(lt);                          // tau
        sc_sh[1] = __logf(1.0f + __expf(ls)) + 0.01f;   // sigma
        sc_sh[2] = __logf(1.0f + __expf(lw));           // w
    }

    // chunked layout: elem j<4 at channel 4*tid+j ; j>=4 at 4*(tid+NT)+(j-4)
    // -> every float4 load is 1KiB wave-contiguous
    float4 xa = ((const float4*)xr)[tid];
    float4 xb = ((const float4*)xr)[tid + NT];
    float4 ma = ((const float4*)ema_mean)[tid];
    float4 mb = ((const float4*)ema_mean)[tid + NT];
    float4 qa = ((const float4*)ema_sq)[tid];
    float4 qb = ((const float4*)ema_sq)[tid + NT];
    float4 ea = ((const float4*)ema_out)[tid];
    float4 eb = ((const float4*)ema_out)[tid + NT];

    float xv[8] = {xa.x,xa.y,xa.z,xa.w, xb.x,xb.y,xb.z,xb.w};
    float mv[8] = {ma.x,ma.y,ma.z,ma.w, mb.x,mb.y,mb.z,mb.w};
    float qv[8] = {qa.x,qa.y,qa.z,qa.w, qb.x,qb.y,qb.z,qb.w};
    float ev[8] = {ea.x,ea.y,ea.z,ea.w, eb.x,eb.y,eb.z,eb.w};

    float g[8], av[8];
    float dot = 0.f, nrm = 0.f, ss = 0.f;
#pragma unroll
    for (int j = 0; j < 8; ++j) {
        float m = mv[j];
        float v = fmaxf(fmaf(-m, m, qv[j]), 1e-6f);     // clip(ema_sq - m^2, 1e-6)
        float z = (xv[j] - m) * __builtin_amdgcn_rsqf(v);
        av[j] = fabsf(z);
        float gg = fast_gelu(xv[j]);
        g[j] = gg;
        dot = fmaf(gg, ev[j], dot);                     // sum out * ema_out
        nrm = fmaf(gg, gg, nrm);                        // ||out||^2
        ss  = fmaf(ev[j], ev[j], ss);                   // ||ema_out||^2
    }

    __syncthreads();   // hist zeros + scalars visible
#pragma unroll
    for (int j = 0; j < 8; ++j) {
        int b = (int)fminf(av[j] * 32.0f, 255.0f);
        atomicAdd(&hist[b], 1);
    }
    __syncthreads();

    // ---- suffix scan from the top bin to locate the K-th boundary bin ----
    {
        int bin = (NBINS - 1) - tid;     // tid 0 -> bin 255
        int h = hist[bin];
        int p = h;
#pragma unroll
        for (int o = 1; o < 64; o <<= 1) {
            int t = __shfl_up(p, o, 64);
            if ((tid & 63) >= o) p += t;
        }
        if ((tid & 63) == 63) wsum[tid >> 6] = p;
        __syncthreads();
        int off = 0;
        for (int wv = 0; wv < (tid >> 6); ++wv) off += wsum[wv];
        int suf_incl = p + off;          // # values in bins >= bin
        int suf_excl = suf_incl - h;     // # values in bins >  bin
        if (suf_excl < KSEL && suf_incl >= KSEL) {
            bsel_sh = bin;
            krem_sh = KSEL - suf_excl;   // how many boundary-bin values count
        }
    }
    __syncthreads();

    const int   bsel = bsel_sh;
    const float hi   = (float)(bsel + 1) * INV_BIN;   // exact fp boundary
    const float mid  = ((float)bsel + 0.5f) * INV_BIN;

    // sum of values strictly above the boundary bin
    float s = 0.f;
#pragma unroll
    for (int j = 0; j < 8; ++j) {
        s += (av[j] >= hi) ? av[j] : 0.f;
    }

    // ---- single fused block reduction of {dot, nrm, ss, s} ----
#pragma unroll
    for (int o = 32; o > 0; o >>= 1) {
        dot += __shfl_down(dot, o, 64);
        nrm += __shfl_down(nrm, o, 64);
        ss  += __shfl_down(ss,  o, 64);
        s   += __shfl_down(s,   o, 64);
    }
    const int wave = tid >> 6;
    if ((tid & 63) == 0) {
        red[wave][0] = dot; red[wave][1] = nrm;
        red[wave][2] = ss;  red[wave][3] = s;
    }
    __syncthreads();
    dot = red[0][0] + red[1][0] + red[2][0] + red[3][0];
    nrm = red[0][1] + red[1][1] + red[2][1] + red[3][1];
    ss  = red[0][2] + red[1][2] + red[2][2] + red[3][2];
    s   = red[0][3] + red[1][3] + red[2][3] + red[3][3];

    const float tau = sc_sh[0], sigma = sc_sh[1], w = sc_sh[2];
    const float topk_mean = (s + (float)krem_sh * mid) * (1.0f / (float)KSEL);
    const float cosv = dot / ((sqrtf(ss) + 1e-8f) * fmaxf(sqrtf(nrm), 1e-12f));
    const float yt = sigma * topk_mean;                 // >= 0
    const float et = __expf(-2.0f * yt);
    const float th = (1.0f - et) * __builtin_amdgcn_rcpf(1.0f + et);  // tanh(yt)
    const float gate = __expf(-tau * cosv) * fmaf(w, th, 1.0f);

    float4 oa, ob;
    oa.x = g[0]*gate; oa.y = g[1]*gate; oa.z = g[2]*gate; oa.w = g[3]*gate;
    ob.x = g[4]*gate; ob.y = g[5]*gate; ob.z = g[6]*gate; ob.w = g[7]*gate;
    float* outr = out + rowoff;
    ((float4*)outr)[tid]      = oa;
    ((float4*)outr)[tid + NT] = ob;
}

extern "C" void kernel_launch(void* const* d_in, const int* in_sizes, int n_in,
                              void* d_out, int out_size, void* d_ws, size_t ws_size,
                              hipStream_t stream) {
    (void)in_sizes; (void)n_in; (void)out_size; (void)d_ws; (void)ws_size;
    const float* x         = (const float*)d_in[0];
    const float* ema_mean  = (const float*)d_in[1];
    const float* ema_sq    = (const float*)d_in[2];
    const float* ema_out   = (const float*)d_in[3];
    const float* log_tau   = (const float*)d_in[4];
    const float* log_sigma = (const float*)d_in[5];
    const float* log_w     = (const float*)d_in[6];
    float* out = (float*)d_out;

    const int rows = 4 * 4096;  // B*T
    fused_kernel<<<rows, NT, 0, stream>>>(x, ema_mean, ema_sq, ema_out,
                                          log_tau, log_sigma, log_w, out);
}

// Round 3
// 51.707 us; speedup vs baseline: 1.5097x; 1.0773x over previous
//
#include <hip/hip_runtime.h>
#include <math.h>

#define D      2048
#define KSEL   256
#define NT     256          // threads per block; NT*8 == D
#define NBINS  256

typedef float vfloat4 __attribute__((ext_vector_type(4)));

// tanh-form GELU: x * sigmoid(1.5957691*x + 0.0713548*x^3)
__device__ __forceinline__ float fast_gelu(float x) {
    float x2 = x * x;
    float t  = fmaf(x2, -0.0713548162f, -1.5957691216f);
    float e  = __expf(x * t);
    return x * __builtin_amdgcn_rcpf(1.0f + e);
}

// ws layout: [0:D) a = 32/std ; [D:2D) b = -32*mean/std ;
//            [2D:3D) u = ema_out/(||ema_out||+1e-8) ; [3D:3D+3) tau,sigma,w
__global__ __launch_bounds__(NT) void prep_kernel(
    const float* __restrict__ ema_mean,
    const float* __restrict__ ema_sq,
    const float* __restrict__ ema_out,
    const float* __restrict__ p_log_tau,
    const float* __restrict__ p_log_sigma,
    const float* __restrict__ p_log_w,
    float* __restrict__ ws)
{
    __shared__ float red[4];
    const int tid = threadIdx.x;
    float ss = 0.f;
#pragma unroll
    for (int k = 0; k < D / NT; ++k) {
        int i = tid + k * NT;
        float m = ema_mean[i];
        float v = fmaxf(fmaf(-m, m, ema_sq[i]), 1e-6f);
        float inv = 32.0f * __builtin_amdgcn_rsqf(v);   // 32/std
        ws[i]     = inv;
        ws[D + i] = -m * inv;
        float e = ema_out[i];
        ss = fmaf(e, e, ss);
    }
#pragma unroll
    for (int o = 32; o > 0; o >>= 1) ss += __shfl_down(ss, o, 64);
    if ((tid & 63) == 0) red[tid >> 6] = ss;
    __syncthreads();
    float inv_nrm = 1.0f / (sqrtf(red[0] + red[1] + red[2] + red[3]) + 1e-8f);
#pragma unroll
    for (int k = 0; k < D / NT; ++k) {
        int i = tid + k * NT;
        ws[2 * D + i] = ema_out[i] * inv_nrm;
    }
    if (tid == 0) {
        ws[3 * D + 0] = __expf(p_log_tau[0]);
        ws[3 * D + 1] = __logf(1.0f + __expf(p_log_sigma[0])) + 0.01f;
        ws[3 * D + 2] = __logf(1.0f + __expf(p_log_w[0]));
    }
}

__global__ __launch_bounds__(NT) void row_kernel(
    const float* __restrict__ x,
    const float* __restrict__ ws,
    float* __restrict__ out)
{
    __shared__ int   hist[NBINS];
    __shared__ int   wsum[4];
    __shared__ float red[4][3];
    __shared__ int   bsel_sh, krem_sh;

    const int tid = threadIdx.x;
    const size_t rowoff = (size_t)blockIdx.x * D;
    const float* __restrict__ xr = x + rowoff;

    hist[tid] = 0;

    // uniform scalar loads
    const float tau   = ws[3 * D + 0];
    const float sigma = ws[3 * D + 1];
    const float w     = ws[3 * D + 2];

    float4 xa = ((const float4*)xr)[tid];
    float4 xb = ((const float4*)xr)[tid + NT];
    float4 aa = ((const float4*)ws)[tid];
    float4 ab = ((const float4*)ws)[tid + NT];
    float4 ba = ((const float4*)(ws + D))[tid];
    float4 bb = ((const float4*)(ws + D))[tid + NT];
    float4 ua = ((const float4*)(ws + 2 * D))[tid];
    float4 ub = ((const float4*)(ws + 2 * D))[tid + NT];

    float xv[8] = {xa.x,xa.y,xa.z,xa.w, xb.x,xb.y,xb.z,xb.w};
    float avv[8] = {aa.x,aa.y,aa.z,aa.w, ab.x,ab.y,ab.z,ab.w};
    float bvv[8] = {ba.x,ba.y,ba.z,ba.w, bb.x,bb.y,bb.z,bb.w};
    float uv[8] = {ua.x,ua.y,ua.z,ua.w, ub.x,ub.y,ub.z,ub.w};

    float g[8], av[8];
    float dot = 0.f, nrm = 0.f;
#pragma unroll
    for (int j = 0; j < 8; ++j) {
        av[j] = fabsf(fmaf(xv[j], avv[j], bvv[j]));   // 32*|z|
        float gg = fast_gelu(xv[j]);
        g[j] = gg;
        dot = fmaf(gg, uv[j], dot);
        nrm = fmaf(gg, gg, nrm);
    }

    __syncthreads();   // hist zeros visible
#pragma unroll
    for (int j = 0; j < 8; ++j) {
        int b = (int)fminf(av[j], 255.0f);
        atomicAdd(&hist[b], 1);
    }
    __syncthreads();

    // suffix scan from the top bin: find boundary bin for K-th largest
    {
        int bin = (NBINS - 1) - tid;
        int h = hist[bin];
        int p = h;
#pragma unroll
        for (int o = 1; o < 64; o <<= 1) {
            int t = __shfl_up(p, o, 64);
            if ((tid & 63) >= o) p += t;
        }
        if ((tid & 63) == 63) wsum[tid >> 6] = p;
        __syncthreads();
        int off = 0;
        for (int wv = 0; wv < (tid >> 6); ++wv) off += wsum[wv];
        int suf_incl = p + off;
        int suf_excl = suf_incl - h;
        if (suf_excl < KSEL && suf_incl >= KSEL) {
            bsel_sh = bin;
            krem_sh = KSEL - suf_excl;
        }
    }
    __syncthreads();

    const int   bsel = bsel_sh;
    // hi: values strictly above the boundary bin; if boundary is the clamp
    // bin (255), nothing is "above" (hist counted clamped values there).
    const float hi  = (bsel == NBINS - 1) ? __builtin_inff() : (float)(bsel + 1);
    const float mid = (float)bsel + 0.5f;

    float s = 0.f;
#pragma unroll
    for (int j = 0; j < 8; ++j) {
        s += (av[j] >= hi) ? av[j] : 0.f;
    }

    // fused block reduction of {dot, nrm, s}
#pragma unroll
    for (int o = 32; o > 0; o >>= 1) {
        dot += __shfl_down(dot, o, 64);
        nrm += __shfl_down(nrm, o, 64);
        s   += __shfl_down(s,   o, 64);
    }
    const int wave = tid >> 6;
    if ((tid & 63) == 0) {
        red[wave][0] = dot; red[wave][1] = nrm; red[wave][2] = s;
    }
    __syncthreads();
    dot = red[0][0] + red[1][0] + red[2][0] + red[3][0];
    nrm = red[0][1] + red[1][1] + red[2][1] + red[3][1];
    s   = red[0][2] + red[1][2] + red[2][2] + red[3][2];

    // scaled units: true topk_sum = (s + krem*mid)/32 ; mean = /KSEL
    const float topk_mean = (s + (float)krem_sh * mid) * (1.0f / (32.0f * KSEL));
    const float cosv = dot * __builtin_amdgcn_rsqf(fmaxf(nrm, 1e-24f));
    const float yt = sigma * topk_mean;
    const float et = __expf(-2.0f * yt);
    const float th = (1.0f - et) * __builtin_amdgcn_rcpf(1.0f + et);
    const float gate = __expf(-tau * cosv) * fmaf(w, th, 1.0f);

    vfloat4 oa, ob;
    oa.x = g[0]*gate; oa.y = g[1]*gate; oa.z = g[2]*gate; oa.w = g[3]*gate;
    ob.x = g[4]*gate; ob.y = g[5]*gate; ob.z = g[6]*gate; ob.w = g[7]*gate;
    vfloat4* outr = (vfloat4*)(out + rowoff);
    __builtin_nontemporal_store(oa, outr + tid);
    __builtin_nontemporal_store(ob, outr + tid + NT);
}

extern "C" void kernel_launch(void* const* d_in, const int* in_sizes, int n_in,
                              void* d_out, int out_size, void* d_ws, size_t ws_size,
                              hipStream_t stream) {
    (void)in_sizes; (void)n_in; (void)out_size; (void)ws_size;
    const float* x         = (const float*)d_in[0];
    const float* ema_mean  = (const float*)d_in[1];
    const float* ema_sq    = (const float*)d_in[2];
    const float* ema_out   = (const float*)d_in[3];
    const float* log_tau   = (const float*)d_in[4];
    const float* log_sigma = (const float*)d_in[5];
    const float* log_w     = (const float*)d_in[6];
    float* out = (float*)d_out;
    float* ws  = (float*)d_ws;

    prep_kernel<<<1, NT, 0, stream>>>(ema_mean, ema_sq, ema_out,
                                      log_tau, log_sigma, log_w, ws);
    const int rows = 4 * 4096;  // B*T
    row_kernel<<<rows, NT, 0, stream>>>(x, ws, out);
}